// Round 3
// baseline (673.540 us; speedup 1.0000x reference)
//
#include <hip/hip_runtime.h>
#include <hip/hip_bf16.h>

// Problem constants (B,S,HID)=(4,8192,1024), H=16, D=64, CHUNK=64, N_BEFORE=1
#define NB 4
#define NS 8192
#define NHID 1024
#define NH 16
#define ND 64
#define NCHUNK 128  // S / 64

typedef __attribute__((ext_vector_type(8))) __bf16 bf16x8;
typedef __attribute__((ext_vector_type(4))) float f32x4;

__device__ __forceinline__ unsigned short f2bf(float x) {
  unsigned int u = __builtin_bit_cast(unsigned int, x);
  unsigned int r = (u + 0x7FFFu + ((u >> 16) & 1u)) >> 16;
  return (unsigned short)r;
}

__device__ __forceinline__ void gload16(const void* g, void* l) {
  __builtin_amdgcn_global_load_lds(
      (const __attribute__((address_space(1))) unsigned int*)g,
      (__attribute__((address_space(3))) unsigned int*)l, 16, 0, 0);
}

// ---------------- X fp32 -> bf16 ----------------
__global__ __launch_bounds__(256) void convert_x(const float* __restrict__ x,
                                                 unsigned short* __restrict__ xb) {
  int gt = blockIdx.x * 256 + threadIdx.x;
  const float4* xf = (const float4*)x;
  float4 v0 = xf[gt * 2 + 0];
  float4 v1 = xf[gt * 2 + 1];
  uint4 o;
  o.x = f2bf(v0.x) | ((unsigned)f2bf(v0.y) << 16);
  o.y = f2bf(v0.z) | ((unsigned)f2bf(v0.w) << 16);
  o.z = f2bf(v1.x) | ((unsigned)f2bf(v1.y) << 16);
  o.w = f2bf(v1.z) | ((unsigned)f2bf(v1.w) << 16);
  ((uint4*)xb)[gt] = o;
}

// ---------------- W [k][n] fp32 -> Wt [3][n][k] bf16 (K scaled by 1/8) -------
__global__ __launch_bounds__(256) void transpose_w(const float* __restrict__ w0,
                                                   const float* __restrict__ w1,
                                                   const float* __restrict__ w2,
                                                   unsigned short* __restrict__ wt) {
  __shared__ float tile[32][33];
  int wi = blockIdx.z;
  const float* w = (wi == 0) ? w0 : ((wi == 1) ? w1 : w2);
  float scale = (wi == 1) ? 0.125f : 1.0f;  // 1/sqrt(D) folded into Wk
  int k0 = blockIdx.x * 32, n0 = blockIdx.y * 32;
  int tx = threadIdx.x, ty = threadIdx.y;  // 32 x 8
#pragma unroll
  for (int i = 0; i < 4; i++)
    tile[ty + i * 8][tx] = w[(k0 + ty + i * 8) * NHID + n0 + tx];
  __syncthreads();
#pragma unroll
  for (int i = 0; i < 4; i++)
    wt[(wi * NHID + n0 + ty + i * 8) * NHID + k0 + tx] =
        f2bf(tile[tx][ty + i * 8] * scale);
}

// ---------------- QKV GEMM: 256x256 tile, BK=64, 8 waves, depth-2 prefetch ---
// T2 swizzle: LDS tile [256][64] bf16, physical 16B-slot = logical_slot ^ (row&7).
// Staged via global_load_lds with pre-swizzled SOURCE column (linear LDS dest).
__device__ __forceinline__ void stage_tile(const unsigned short* __restrict__ src,
                                           size_t row0, int kt, char* ldst,
                                           int tid) {
#pragma unroll
  for (int i = 0; i < 4; i++) {
    int g = tid + i * 512;             // 2048 granules of 16B per 32KB tile
    int r = g >> 3;                    // 8 granules per 128B row
    int slot = (g & 7) ^ (r & 7);      // inverse swizzle on the source side
    gload16(src + (row0 + r) * NHID + kt * 64 + slot * 8, ldst + g * 16);
  }
}

__global__ __launch_bounds__(512, 2) void gemm_qkv(
    const unsigned short* __restrict__ xb, const unsigned short* __restrict__ wt,
    unsigned short* __restrict__ qg, unsigned short* __restrict__ kg,
    unsigned short* __restrict__ vg) {
  __shared__ alignas(16) char smem[131072];  // A[2][256][64] @0, B[2][256][64] @64K
  int bid = blockIdx.x;
  // XCD-aware swizzle (bijective: 1536 % 8 == 0): each XCD gets 192 consecutive
  // logical ids -> 16 consecutive A-panels per XCD L2.
  int wg = (bid & 7) * 192 + (bid >> 3);
  int bm = wg / 12, bn = wg % 12;  // bn fast: A panel reused across 12 bn
  int tid = threadIdx.x;
  int l = tid & 63, lg = l >> 4, lm = l & 15;
  int w = tid >> 6, wm = w >> 2, wn = w & 3;  // 2x4 waves, each owns 128x64 out

  const size_t arow0 = (size_t)bm * 256;
  const size_t brow0 = (size_t)bn * 256;

  // prologue: stage tiles 0,1 ; wait oldest 8 (= tile 0) ; barrier
  stage_tile(xb, arow0, 0, smem + 0, tid);
  stage_tile(wt, brow0, 0, smem + 65536, tid);
  stage_tile(xb, arow0, 1, smem + 32768, tid);
  stage_tile(wt, brow0, 1, smem + 98304, tid);
  asm volatile("s_waitcnt vmcnt(8)" ::: "memory");
  __builtin_amdgcn_s_barrier();
  asm volatile("" ::: "memory");

  f32x4 acc[8][4] = {};

  for (int t = 0; t < 16; ++t) {
    const char* Ab = smem + (t & 1) * 32768;
    const char* Bb = smem + 65536 + (t & 1) * 32768;
    bf16x8 av[8][2], bv[4][2];
#pragma unroll
    for (int mi = 0; mi < 8; mi++)
#pragma unroll
      for (int ks = 0; ks < 2; ks++) {
        int row = wm * 128 + mi * 16 + lm;
        int byte = (row * 128 + ks * 64 + lg * 16) ^ ((row & 7) << 4);
        av[mi][ks] = *reinterpret_cast<const bf16x8*>(Ab + byte);
      }
#pragma unroll
    for (int ni = 0; ni < 4; ni++)
#pragma unroll
      for (int ks = 0; ks < 2; ks++) {
        int row = wn * 64 + ni * 16 + lm;
        int byte = (row * 128 + ks * 64 + lg * 16) ^ ((row & 7) << 4);
        bv[ni][ks] = *reinterpret_cast<const bf16x8*>(Bb + byte);
      }
#pragma unroll
    for (int q = 0; q < 4; q++) {
      __builtin_amdgcn_s_setprio(1);
#pragma unroll
      for (int mi = 2 * q; mi < 2 * q + 2; mi++)
#pragma unroll
        for (int ni = 0; ni < 4; ni++)
#pragma unroll
          for (int ks = 0; ks < 2; ks++)
            acc[mi][ni] = __builtin_amdgcn_mfma_f32_16x16x32_bf16(
                av[mi][ks], bv[ni][ks], acc[mi][ni], 0, 0, 0);
      __builtin_amdgcn_s_setprio(0);
    }
    // all waves done READING buf(t) -> safe to overwrite with tile t+2
    asm volatile("s_waitcnt lgkmcnt(0)" ::: "memory");
    __builtin_amdgcn_s_barrier();
    asm volatile("" ::: "memory");
    if (t < 14) {
      stage_tile(xb, arow0, t + 2, (char*)smem + (t & 1) * 32768, tid);
      stage_tile(wt, brow0, t + 2, (char*)smem + 65536 + (t & 1) * 32768, tid);
      // outstanding = residual(t+1) + 8(t+2); wait until only t+2 remains
      asm volatile("s_waitcnt vmcnt(8)" ::: "memory");
    } else {
      asm volatile("s_waitcnt vmcnt(0)" ::: "memory");
    }
    __builtin_amdgcn_s_barrier();
    asm volatile("" ::: "memory");
  }

  // epilogue: scatter to [b][h][s][d] bf16; tile spans one weight (bn>>2)
  int wsel = bn >> 2;
  unsigned short* dst = (wsel == 0) ? qg : ((wsel == 1) ? kg : vg);
  int n0 = (bn & 3) * 256;
#pragma unroll
  for (int mi = 0; mi < 8; mi++)
#pragma unroll
    for (int ni = 0; ni < 4; ni++)
#pragma unroll
      for (int r = 0; r < 4; r++) {
        int gm = bm * 256 + wm * 128 + mi * 16 + lg * 4 + r;  // row = m (= b,s)
        int n = n0 + wn * 64 + ni * 16 + lm;                  // col within weight
        int b = gm >> 13, s = gm & (NS - 1);
        int h = n >> 6, d = n & (ND - 1);
        dst[(((size_t)(b * NH + h) * NS) + s) * ND + d] = f2bf(acc[mi][ni][r]);
      }
}

// ---------------- Local attention: block = (chunk c, head h, batch b) --------
// 4 waves x 16 q-rows. 40KB LDS (P aliases Q+K halves) -> 4 blocks/CU.
// V loaded to regs early (latency overlapped), scattered to LDS after QK^T.
__global__ __launch_bounds__(256, 4) void attn_local(
    const unsigned short* __restrict__ qg, const unsigned short* __restrict__ kg,
    const unsigned short* __restrict__ vg, float* __restrict__ out) {
  __shared__ alignas(16) char lds[40960];
  unsigned short* qs = (unsigned short*)lds;             // [64][64] swz, 8KB
  unsigned short* ks2 = (unsigned short*)(lds + 8192);   // [128][64] swz, 16KB
  unsigned short* vts = (unsigned short*)(lds + 24576);  // [64][128] swz, 16KB
  char* psb = lds;  // P [64][128] swz, 16KB — ALIASES qs + ks2[0:64) after b2
  int c = blockIdx.x, h = blockIdx.y, b = blockIdx.z;
  int t = threadIdx.x;
  int w = t >> 6, l = t & 63, lg = l >> 4, lm = l & 15;
  size_t bhbase = (size_t)(b * NH + h) * NS * ND;
  int kv0 = (c - 1) * 64;  // global s of kv col 0 (negative for c==0: masked)

  // ---- early V loads to registers (T14: issue early, LDS-write late) ----
  int kq = t >> 1, half = t & 1;
  int sv = kv0 + kq;
  if (sv < 0) sv = 0;
  uint4 vreg[4];
#pragma unroll
  for (int i = 0; i < 4; i++)
    vreg[i] = *reinterpret_cast<const uint4*>(vg + bhbase + (size_t)sv * ND +
                                              half * 32 + i * 8);

  // stage Q [64][64], XOR-swizzled rows (stride 128B)
#pragma unroll
  for (int i = 0; i < 2; i++) {
    int g = t + i * 256;
    int row = g >> 3, cc = g & 7;
    uint4 v = *reinterpret_cast<const uint4*>(qg + bhbase +
                                              (size_t)(c * 64 + row) * ND + cc * 8);
    int byte = (row * 128 + cc * 16) ^ ((row & 7) << 4);
    *reinterpret_cast<uint4*>(lds + byte) = v;
  }
  // stage K [128][64]
#pragma unroll
  for (int i = 0; i < 4; i++) {
    int g = t + i * 256;
    int row = g >> 3, cc = g & 7;
    int s = kv0 + row;
    if (s < 0) s = 0;  // garbage rows fully masked later
    uint4 v = *reinterpret_cast<const uint4*>(kg + bhbase + (size_t)s * ND + cc * 8);
    int byte = (row * 128 + cc * 16) ^ ((row & 7) << 4);
    *reinterpret_cast<uint4*>(lds + 8192 + byte) = v;
  }
  __syncthreads();  // b1

  // ---- S = Q K^T : wave w owns q rows [w*16, w*16+16), all 128 kv cols ----
  bf16x8 qa[2];
#pragma unroll
  for (int ks = 0; ks < 2; ks++) {
    int row = w * 16 + lm;
    int byte = (row * 128 + (ks * 32 + lg * 8) * 2) ^ ((row & 7) << 4);
    qa[ks] = *reinterpret_cast<const bf16x8*>((char*)qs + byte);
  }
  f32x4 sf[8];
#pragma unroll
  for (int nt = 0; nt < 8; nt++) {
    f32x4 a = {};
#pragma unroll
    for (int ks = 0; ks < 2; ks++) {
      int n = nt * 16 + lm;
      int byte = (n * 128 + (ks * 32 + lg * 8) * 2) ^ ((n & 7) << 4);
      bf16x8 kb = *reinterpret_cast<const bf16x8*>((char*)ks2 + byte);
      a = __builtin_amdgcn_mfma_f32_16x16x32_bf16(qa[ks], kb, a, 0, 0, 0);
    }
    sf[nt] = a;  // S[q = w*16+lg*4+r][kv = nt*16+lm]
  }

  // ---- masked softmax, rows stay in 16-lane groups ----
  float mx[4] = {-1e30f, -1e30f, -1e30f, -1e30f};
#pragma unroll
  for (int nt = 0; nt < 8; nt++) {
    int j = nt * 16 + lm;
#pragma unroll
    for (int r = 0; r < 4; r++) {
      int q = w * 16 + lg * 4 + r;
      bool valid = (j <= q + 64) && (c > 0 || j >= 64);
      if (valid) mx[r] = fmaxf(mx[r], sf[nt][r]);
    }
  }
#pragma unroll
  for (int r = 0; r < 4; r++)
#pragma unroll
    for (int d = 1; d < 16; d <<= 1) mx[r] = fmaxf(mx[r], __shfl_xor(mx[r], d, 64));

  float sum[4] = {0.f, 0.f, 0.f, 0.f};
#pragma unroll
  for (int nt = 0; nt < 8; nt++) {
    int j = nt * 16 + lm;
#pragma unroll
    for (int r = 0; r < 4; r++) {
      int q = w * 16 + lg * 4 + r;
      bool valid = (j <= q + 64) && (c > 0 || j >= 64);
      float p = valid ? __expf(sf[nt][r] - mx[r]) : 0.0f;
      sf[nt][r] = p;
      sum[r] += p;
    }
  }
#pragma unroll
  for (int r = 0; r < 4; r++)
#pragma unroll
    for (int d = 1; d < 16; d <<= 1) sum[r] += __shfl_xor(sum[r], d, 64);

  __syncthreads();  // b2: all QK^T reads of qs/ks2 done -> P may overwrite them

  // write P (bf16) to aliased LDS [q][kv]
#pragma unroll
  for (int nt = 0; nt < 8; nt++) {
    int j = nt * 16 + lm;
#pragma unroll
    for (int r = 0; r < 4; r++) {
      int q = w * 16 + lg * 4 + r;
      int byte = (q * 256 + j * 2) ^ ((q & 7) << 4);
      *reinterpret_cast<unsigned short*>(psb + byte) = f2bf(sf[nt][r]);
    }
  }
  // scatter V regs -> vts[d][kv] transposed, col ^= (d&7)<<3
  {
    unsigned short* vtse = (unsigned short*)vts;
#pragma unroll
    for (int i = 0; i < 4; i++) {
      int d0 = half * 32 + i * 8;
      unsigned int u[4] = {vreg[i].x, vreg[i].y, vreg[i].z, vreg[i].w};
#pragma unroll
      for (int j = 0; j < 8; j++) {
        unsigned short val = (unsigned short)(u[j >> 1] >> ((j & 1) * 16));
        vtse[(d0 + j) * 128 + (kq ^ (j << 3))] = val;  // (d0+j)&7 == j
      }
    }
  }
  __syncthreads();  // b3

  // ---- O = P V : A = P rows (q), B = vts rows (d) ----
  bf16x8 pa[4];
#pragma unroll
  for (int ks = 0; ks < 4; ks++) {
    int q = w * 16 + lm;
    int byte = (q * 256 + (ks * 32 + lg * 8) * 2) ^ ((q & 7) << 4);
    pa[ks] = *reinterpret_cast<const bf16x8*>(psb + byte);
  }
  float rcpl[4];
#pragma unroll
  for (int r = 0; r < 4; r++) rcpl[r] = 1.0f / sum[r];
#pragma unroll
  for (int nt = 0; nt < 4; nt++) {
    f32x4 o = {};
#pragma unroll
    for (int ks = 0; ks < 4; ks++) {
      int dn = nt * 16 + lm;
      int byte = (dn * 256 + (ks * 32 + lg * 8) * 2) ^ ((dn & 7) << 4);
      bf16x8 vb = *reinterpret_cast<const bf16x8*>((char*)vts + byte);
      o = __builtin_amdgcn_mfma_f32_16x16x32_bf16(pa[ks], vb, o, 0, 0, 0);
    }
#pragma unroll
    for (int r = 0; r < 4; r++) {
      int sq = c * 64 + w * 16 + lg * 4 + r;
      int d = nt * 16 + lm;
      out[(size_t)(b * NS + sq) * (NH * ND) + h * ND + d] = o[r] * rcpl[r];
    }
  }
}

// ---------------- launch ----------------
extern "C" void kernel_launch(void* const* d_in, const int* in_sizes, int n_in,
                              void* d_out, int out_size, void* d_ws, size_t ws_size,
                              hipStream_t stream) {
  const float* hs = (const float*)d_in[0];
  const float* wq = (const float*)d_in[1];
  const float* wk = (const float*)d_in[2];
  const float* wv = (const float*)d_in[3];
  float* out = (float*)d_out;
  char* ws = (char*)d_ws;

  const size_t XB_BYTES = (size_t)NB * NS * NHID * 2;      // 64MB
  const size_t WT_BYTES = (size_t)3 * NHID * NHID * 2;     // 6MB
  const size_t QKV_BYTES = (size_t)NB * NH * NS * ND * 2;  // 64MB each
  unsigned short* xb = (unsigned short*)ws;
  unsigned short* wt = (unsigned short*)(ws + XB_BYTES);
  unsigned short* qg = (unsigned short*)(ws + XB_BYTES + WT_BYTES);
  unsigned short* kg = (unsigned short*)(ws + XB_BYTES + WT_BYTES + QKV_BYTES);
  unsigned short* vg = (unsigned short*)(ws + XB_BYTES + WT_BYTES + 2 * QKV_BYTES);

  hipLaunchKernelGGL(convert_x, dim3((NB * NS * NHID) / (256 * 8)), dim3(256), 0,
                     stream, hs, xb);
  hipLaunchKernelGGL(transpose_w, dim3(32, 32, 3), dim3(32, 8), 0, stream, wq, wk,
                     wv, wt);
  hipLaunchKernelGGL(gemm_qkv, dim3(128 * 12), dim3(512), 0, stream, xb, wt, qg,
                     kg, vg);
  hipLaunchKernelGGL(attn_local, dim3(NCHUNK, NH, NB), dim3(256), 0, stream, qg,
                     kg, vg, out);
}

// Round 4
// 498.865 us; speedup vs baseline: 1.3501x; 1.3501x over previous
//
#include <hip/hip_runtime.h>
#include <hip/hip_bf16.h>

// Problem constants (B,S,HID)=(4,8192,1024), H=16, D=64, CHUNK=64, N_BEFORE=1
#define NB 4
#define NS 8192
#define NHID 1024
#define NH 16
#define ND 64
#define NCHUNK 128  // S / 64

typedef __attribute__((ext_vector_type(8))) __bf16 bf16x8;
typedef __attribute__((ext_vector_type(4))) float f32x4;

__device__ __forceinline__ unsigned short f2bf(float x) {
  unsigned int u = __builtin_bit_cast(unsigned int, x);
  unsigned int r = (u + 0x7FFFu + ((u >> 16) & 1u)) >> 16;
  return (unsigned short)r;
}

__device__ __forceinline__ void gload16(const void* g, void* l) {
  __builtin_amdgcn_global_load_lds(
      (const __attribute__((address_space(1))) unsigned int*)g,
      (__attribute__((address_space(3))) unsigned int*)l, 16, 0, 0);
}

#define BAR()                        \
  asm volatile("" ::: "memory");     \
  __builtin_amdgcn_s_barrier();      \
  asm volatile("" ::: "memory")

// ---------------- X fp32 -> bf16 ----------------
__global__ __launch_bounds__(256) void convert_x(const float* __restrict__ x,
                                                 unsigned short* __restrict__ xb) {
  int gt = blockIdx.x * 256 + threadIdx.x;
  const float4* xf = (const float4*)x;
  float4 v0 = xf[gt * 2 + 0];
  float4 v1 = xf[gt * 2 + 1];
  uint4 o;
  o.x = f2bf(v0.x) | ((unsigned)f2bf(v0.y) << 16);
  o.y = f2bf(v0.z) | ((unsigned)f2bf(v0.w) << 16);
  o.z = f2bf(v1.x) | ((unsigned)f2bf(v1.y) << 16);
  o.w = f2bf(v1.z) | ((unsigned)f2bf(v1.w) << 16);
  ((uint4*)xb)[gt] = o;
}

// ---------------- W [k][n] fp32 -> Wt [3][n][k] bf16 (K scaled by 1/8) -------
__global__ __launch_bounds__(256) void transpose_w(const float* __restrict__ w0,
                                                   const float* __restrict__ w1,
                                                   const float* __restrict__ w2,
                                                   unsigned short* __restrict__ wt) {
  __shared__ float tile[32][33];
  int wi = blockIdx.z;
  const float* w = (wi == 0) ? w0 : ((wi == 1) ? w1 : w2);
  float scale = (wi == 1) ? 0.125f : 1.0f;  // 1/sqrt(D) folded into Wk
  int k0 = blockIdx.x * 32, n0 = blockIdx.y * 32;
  int tx = threadIdx.x, ty = threadIdx.y;  // 32 x 8
#pragma unroll
  for (int i = 0; i < 4; i++)
    tile[ty + i * 8][tx] = w[(k0 + ty + i * 8) * NHID + n0 + tx];
  __syncthreads();
#pragma unroll
  for (int i = 0; i < 4; i++)
    wt[(wi * NHID + n0 + ty + i * 8) * NHID + k0 + tx] =
        f2bf(tile[tx][ty + i * 8] * scale);
}

// ---------------- QKV GEMM: 256x256, BK=64, 8 waves, 4-phase/K-tile pipeline -
// LDS: per dbuf {A-h0, A-h1, B-h0, B-h1} of [128][64] bf16 (16KB each, swizzled
// slot = logical ^ (row&7)). Phase (qm,qn) reads ONLY A-half qm / B-half qn
// because wave output rows interleave: row = qm*128 + wm*64 + ..., col =
// qn*128 + wn*32 + ... . Staging: during tile t issue (t+1).Ah1, (t+1).Bh1,
// (t+2).Ah0, (t+2).Bh0 — each after its slot's last-read phase + barrier.
// vmcnt(4) once per K-tile (2 half-tiles in flight), never 0 until the tail.
#define OFF_A0 0
#define OFF_A1 16384
#define OFF_B0 32768
#define OFF_B1 49152

__device__ __forceinline__ void stage_half(const unsigned short* __restrict__ src,
                                           size_t row0, int kt, char* ldsbase,
                                           int tid) {
#pragma unroll
  for (int i = 0; i < 2; i++) {
    int g = tid + i * 512;         // 1024 granules of 16B per 16KB half-tile
    int r = g >> 3;                // 8 granules per 128B row
    int slot = (g & 7) ^ (r & 7);  // inverse swizzle on the source side
    gload16(src + (row0 + r) * NHID + kt * 64 + slot * 8, ldsbase + g * 16);
  }
}

__device__ __forceinline__ bf16x8 lds_frag(const char* base, int r, int ks,
                                           int lg) {
  int byte = (r * 128 + ks * 64 + lg * 16) ^ ((r & 7) << 4);
  return *reinterpret_cast<const bf16x8*>(base + byte);
}

#define MFMA16(ACC, AF, BF)                                                  \
  __builtin_amdgcn_s_setprio(1);                                             \
  _Pragma("unroll") for (int mi = 0; mi < 4; mi++)                           \
      _Pragma("unroll") for (int ni = 0; ni < 2; ni++)                       \
          _Pragma("unroll") for (int ks = 0; ks < 2; ks++)                   \
              ACC[mi][ni] = __builtin_amdgcn_mfma_f32_16x16x32_bf16(         \
                  AF[mi][ks], BF[ni][ks], ACC[mi][ni], 0, 0, 0);             \
  __builtin_amdgcn_s_setprio(0)

__global__ __launch_bounds__(512, 2) void gemm_qkv(
    const unsigned short* __restrict__ xb, const unsigned short* __restrict__ wt,
    unsigned short* __restrict__ qg, unsigned short* __restrict__ kg,
    unsigned short* __restrict__ vg) {
  __shared__ alignas(16) char smem[131072];  // 2 dbuf x 64KB
  int bid = blockIdx.x;
  // XCD-aware swizzle (bijective: 1536 % 8 == 0)
  int wg = (bid & 7) * 192 + (bid >> 3);
  int bm = wg / 12, bn = wg % 12;  // bn fast: A panel reused across 12 bn
  int tid = threadIdx.x;
  int l = tid & 63, lg = l >> 4, lm = l & 15;
  int w = tid >> 6, wm = w >> 2, wn = w & 3;  // 2x4 waves

  const size_t arow0 = (size_t)bm * 256;
  const size_t brow0 = (size_t)bn * 256;

  // prologue: tile0 complete + tile1 {Ah0,Bh0}; wait all but last 2 halves
  stage_half(xb, arow0, 0, smem + OFF_A0, tid);
  stage_half(wt, brow0, 0, smem + OFF_B0, tid);
  stage_half(xb, arow0 + 128, 0, smem + OFF_A1, tid);
  stage_half(wt, brow0 + 128, 0, smem + OFF_B1, tid);
  stage_half(xb, arow0, 1, smem + 65536 + OFF_A0, tid);
  stage_half(wt, brow0, 1, smem + 65536 + OFF_B0, tid);
  asm volatile("s_waitcnt vmcnt(4)" ::: "memory");
  BAR();

  f32x4 acc[2][2][4][2] = {};  // [qm][qn][mi][ni] -> AGPRs
  bf16x8 a[4][2], b0[2][2], b1[2][2];

#pragma unroll 1
  for (int t = 0; t < 16; ++t) {
    char* cb = smem + (t & 1) * 65536;
    char* nb = smem + ((t & 1) ^ 1) * 65536;

    // ---- phase 1 (qm0,qn0): read A0 + B0 ; stage (t+1).Ah1 ----
#pragma unroll
    for (int mi = 0; mi < 4; mi++)
#pragma unroll
      for (int ks = 0; ks < 2; ks++)
        a[mi][ks] = lds_frag(cb + OFF_A0, wm * 64 + mi * 16 + lm, ks, lg);
#pragma unroll
    for (int ni = 0; ni < 2; ni++)
#pragma unroll
      for (int ks = 0; ks < 2; ks++)
        b0[ni][ks] = lds_frag(cb + OFF_B0, wn * 32 + ni * 16 + lm, ks, lg);
    if (t < 15) stage_half(xb, arow0 + 128, t + 1, nb + OFF_A1, tid);
    BAR();
    MFMA16(acc[0][0], a, b0);
    BAR();

    // ---- phase 2 (qm0,qn1): read B1 ; stage (t+1).Bh1 ----
#pragma unroll
    for (int ni = 0; ni < 2; ni++)
#pragma unroll
      for (int ks = 0; ks < 2; ks++)
        b1[ni][ks] = lds_frag(cb + OFF_B1, wn * 32 + ni * 16 + lm, ks, lg);
    if (t < 15) stage_half(wt, brow0 + 128, t + 1, nb + OFF_B1, tid);
    BAR();
    MFMA16(acc[0][1], a, b1);
    BAR();

    // ---- phase 3 (qm1,qn0): read A1 ; stage (t+2).Ah0 (slot free since P2) --
#pragma unroll
    for (int mi = 0; mi < 4; mi++)
#pragma unroll
      for (int ks = 0; ks < 2; ks++)
        a[mi][ks] = lds_frag(cb + OFF_A1, wm * 64 + mi * 16 + lm, ks, lg);
    if (t < 14) stage_half(xb, arow0, t + 2, cb + OFF_A0, tid);
    BAR();
    MFMA16(acc[1][0], a, b0);
    BAR();

    // ---- phase 4 (qm1,qn1): stage (t+2).Bh0 ; counted vmcnt ----
    if (t < 14) {
      stage_half(wt, brow0, t + 2, cb + OFF_B0, tid);
      asm volatile("s_waitcnt vmcnt(4)" ::: "memory");
    } else {
      asm volatile("s_waitcnt vmcnt(0)" ::: "memory");
    }
    BAR();
    MFMA16(acc[1][1], a, b1);
    BAR();
  }

  // epilogue: scatter to [b][h][s][d] bf16; tile spans one weight (bn>>2)
  int wsel = bn >> 2;
  unsigned short* dst = (wsel == 0) ? qg : ((wsel == 1) ? kg : vg);
#pragma unroll
  for (int qm = 0; qm < 2; qm++)
#pragma unroll
    for (int qn = 0; qn < 2; qn++)
#pragma unroll
      for (int mi = 0; mi < 4; mi++)
#pragma unroll
        for (int ni = 0; ni < 2; ni++)
#pragma unroll
          for (int rr = 0; rr < 4; rr++) {
            int gm = bm * 256 + qm * 128 + wm * 64 + mi * 16 + lg * 4 + rr;
            int n = (bn & 3) * 256 + qn * 128 + wn * 32 + ni * 16 + lm;
            int b = gm >> 13, s = gm & (NS - 1);
            int h = n >> 6, d = n & (ND - 1);
            dst[(((size_t)(b * NH + h) * NS) + s) * ND + d] =
                f2bf(acc[qm][qn][mi][ni][rr]);
          }
}

// ---------------- Local attention: block = (chunk c, head h, batch b) --------
// 4 waves x 16 q-rows. 40KB LDS (P aliases Q+K halves) -> 4 blocks/CU.
// V loaded to regs early (latency overlapped), scattered to LDS after QK^T.
__global__ __launch_bounds__(256, 4) void attn_local(
    const unsigned short* __restrict__ qg, const unsigned short* __restrict__ kg,
    const unsigned short* __restrict__ vg, float* __restrict__ out) {
  __shared__ alignas(16) char lds[40960];
  unsigned short* qs = (unsigned short*)lds;             // [64][64] swz, 8KB
  unsigned short* ks2 = (unsigned short*)(lds + 8192);   // [128][64] swz, 16KB
  unsigned short* vts = (unsigned short*)(lds + 24576);  // [64][128] swz, 16KB
  char* psb = lds;  // P [64][128] swz, 16KB — ALIASES qs + ks2[0:64) after b2
  int c = blockIdx.x, h = blockIdx.y, b = blockIdx.z;
  int t = threadIdx.x;
  int w = t >> 6, l = t & 63, lg = l >> 4, lm = l & 15;
  size_t bhbase = (size_t)(b * NH + h) * NS * ND;
  int kv0 = (c - 1) * 64;  // global s of kv col 0 (negative for c==0: masked)

  // ---- early V loads to registers (T14: issue early, LDS-write late) ----
  int kq = t >> 1, half = t & 1;
  int sv = kv0 + kq;
  if (sv < 0) sv = 0;
  uint4 vreg[4];
#pragma unroll
  for (int i = 0; i < 4; i++)
    vreg[i] = *reinterpret_cast<const uint4*>(vg + bhbase + (size_t)sv * ND +
                                              half * 32 + i * 8);

  // stage Q [64][64], XOR-swizzled rows (stride 128B)
#pragma unroll
  for (int i = 0; i < 2; i++) {
    int g = t + i * 256;
    int row = g >> 3, cc = g & 7;
    uint4 v = *reinterpret_cast<const uint4*>(qg + bhbase +
                                              (size_t)(c * 64 + row) * ND + cc * 8);
    int byte = (row * 128 + cc * 16) ^ ((row & 7) << 4);
    *reinterpret_cast<uint4*>(lds + byte) = v;
  }
  // stage K [128][64]
#pragma unroll
  for (int i = 0; i < 4; i++) {
    int g = t + i * 256;
    int row = g >> 3, cc = g & 7;
    int s = kv0 + row;
    if (s < 0) s = 0;  // garbage rows fully masked later
    uint4 v = *reinterpret_cast<const uint4*>(kg + bhbase + (size_t)s * ND + cc * 8);
    int byte = (row * 128 + cc * 16) ^ ((row & 7) << 4);
    *reinterpret_cast<uint4*>(lds + 8192 + byte) = v;
  }
  __syncthreads();  // b1

  // ---- S = Q K^T : wave w owns q rows [w*16, w*16+16), all 128 kv cols ----
  bf16x8 qa[2];
#pragma unroll
  for (int ks = 0; ks < 2; ks++) {
    int row = w * 16 + lm;
    int byte = (row * 128 + (ks * 32 + lg * 8) * 2) ^ ((row & 7) << 4);
    qa[ks] = *reinterpret_cast<const bf16x8*>((char*)qs + byte);
  }
  f32x4 sf[8];
#pragma unroll
  for (int nt = 0; nt < 8; nt++) {
    f32x4 a = {};
#pragma unroll
    for (int ks = 0; ks < 2; ks++) {
      int n = nt * 16 + lm;
      int byte = (n * 128 + (ks * 32 + lg * 8) * 2) ^ ((n & 7) << 4);
      bf16x8 kb = *reinterpret_cast<const bf16x8*>((char*)ks2 + byte);
      a = __builtin_amdgcn_mfma_f32_16x16x32_bf16(qa[ks], kb, a, 0, 0, 0);
    }
    sf[nt] = a;  // S[q = w*16+lg*4+r][kv = nt*16+lm]
  }

  // ---- masked softmax, rows stay in 16-lane groups ----
  float mx[4] = {-1e30f, -1e30f, -1e30f, -1e30f};
#pragma unroll
  for (int nt = 0; nt < 8; nt++) {
    int j = nt * 16 + lm;
#pragma unroll
    for (int r = 0; r < 4; r++) {
      int q = w * 16 + lg * 4 + r;
      bool valid = (j <= q + 64) && (c > 0 || j >= 64);
      if (valid) mx[r] = fmaxf(mx[r], sf[nt][r]);
    }
  }
#pragma unroll
  for (int r = 0; r < 4; r++)
#pragma unroll
    for (int d = 1; d < 16; d <<= 1) mx[r] = fmaxf(mx[r], __shfl_xor(mx[r], d, 64));

  float sum[4] = {0.f, 0.f, 0.f, 0.f};
#pragma unroll
  for (int nt = 0; nt < 8; nt++) {
    int j = nt * 16 + lm;
#pragma unroll
    for (int r = 0; r < 4; r++) {
      int q = w * 16 + lg * 4 + r;
      bool valid = (j <= q + 64) && (c > 0 || j >= 64);
      float p = valid ? __expf(sf[nt][r] - mx[r]) : 0.0f;
      sf[nt][r] = p;
      sum[r] += p;
    }
  }
#pragma unroll
  for (int r = 0; r < 4; r++)
#pragma unroll
    for (int d = 1; d < 16; d <<= 1) sum[r] += __shfl_xor(sum[r], d, 64);

  __syncthreads();  // b2: all QK^T reads of qs/ks2 done -> P may overwrite them

  // write P (bf16) to aliased LDS [q][kv]
#pragma unroll
  for (int nt = 0; nt < 8; nt++) {
    int j = nt * 16 + lm;
#pragma unroll
    for (int r = 0; r < 4; r++) {
      int q = w * 16 + lg * 4 + r;
      int byte = (q * 256 + j * 2) ^ ((q & 7) << 4);
      *reinterpret_cast<unsigned short*>(psb + byte) = f2bf(sf[nt][r]);
    }
  }
  // scatter V regs -> vts[d][kv] transposed, col ^= (d&7)<<3
  {
    unsigned short* vtse = (unsigned short*)vts;
#pragma unroll
    for (int i = 0; i < 4; i++) {
      int d0 = half * 32 + i * 8;
      unsigned int u[4] = {vreg[i].x, vreg[i].y, vreg[i].z, vreg[i].w};
#pragma unroll
      for (int j = 0; j < 8; j++) {
        unsigned short val = (unsigned short)(u[j >> 1] >> ((j & 1) * 16));
        vtse[(d0 + j) * 128 + (kq ^ (j << 3))] = val;  // (d0+j)&7 == j
      }
    }
  }
  __syncthreads();  // b3

  // ---- O = P V : A = P rows (q), B = vts rows (d) ----
  bf16x8 pa[4];
#pragma unroll
  for (int ks = 0; ks < 4; ks++) {
    int q = w * 16 + lm;
    int byte = (q * 256 + (ks * 32 + lg * 8) * 2) ^ ((q & 7) << 4);
    pa[ks] = *reinterpret_cast<const bf16x8*>(psb + byte);
  }
  float rcpl[4];
#pragma unroll
  for (int r = 0; r < 4; r++) rcpl[r] = 1.0f / sum[r];
#pragma unroll
  for (int nt = 0; nt < 4; nt++) {
    f32x4 o = {};
#pragma unroll
    for (int ks = 0; ks < 4; ks++) {
      int dn = nt * 16 + lm;
      int byte = (dn * 256 + (ks * 32 + lg * 8) * 2) ^ ((dn & 7) << 4);
      bf16x8 vb = *reinterpret_cast<const bf16x8*>((char*)vts + byte);
      o = __builtin_amdgcn_mfma_f32_16x16x32_bf16(pa[ks], vb, o, 0, 0, 0);
    }
#pragma unroll
    for (int r = 0; r < 4; r++) {
      int sq = c * 64 + w * 16 + lg * 4 + r;
      int d = nt * 16 + lm;
      out[(size_t)(b * NS + sq) * (NH * ND) + h * ND + d] = o[r] * rcpl[r];
    }
  }
}

// ---------------- launch ----------------
extern "C" void kernel_launch(void* const* d_in, const int* in_sizes, int n_in,
                              void* d_out, int out_size, void* d_ws, size_t ws_size,
                              hipStream_t stream) {
  const float* hs = (const float*)d_in[0];
  const float* wq = (const float*)d_in[1];
  const float* wk = (const float*)d_in[2];
  const float* wv = (const float*)d_in[3];
  float* out = (float*)d_out;
  char* ws = (char*)d_ws;

  const size_t XB_BYTES = (size_t)NB * NS * NHID * 2;      // 64MB
  const size_t WT_BYTES = (size_t)3 * NHID * NHID * 2;     // 6MB
  const size_t QKV_BYTES = (size_t)NB * NH * NS * ND * 2;  // 64MB each
  unsigned short* xb = (unsigned short*)ws;
  unsigned short* wt = (unsigned short*)(ws + XB_BYTES);
  unsigned short* qg = (unsigned short*)(ws + XB_BYTES + WT_BYTES);
  unsigned short* kg = (unsigned short*)(ws + XB_BYTES + WT_BYTES + QKV_BYTES);
  unsigned short* vg = (unsigned short*)(ws + XB_BYTES + WT_BYTES + 2 * QKV_BYTES);

  hipLaunchKernelGGL(convert_x, dim3((NB * NS * NHID) / (256 * 8)), dim3(256), 0,
                     stream, hs, xb);
  hipLaunchKernelGGL(transpose_w, dim3(32, 32, 3), dim3(32, 8), 0, stream, wq, wk,
                     wv, wt);
  hipLaunchKernelGGL(gemm_qkv, dim3(128 * 12), dim3(512), 0, stream, xb, wt, qg,
                     kg, vg);
  hipLaunchKernelGGL(attn_local, dim3(NCHUNK, NH, NB), dim3(256), 0, stream, qg,
                     kg, vg, out);
}

// Round 8
// 498.508 us; speedup vs baseline: 1.3511x; 1.0007x over previous
//
#include <hip/hip_runtime.h>
#include <hip/hip_bf16.h>

// Problem constants (B,S,HID)=(4,8192,1024), H=16, D=64, CHUNK=64, N_BEFORE=1
#define NB 4
#define NS 8192
#define NHID 1024
#define NH 16
#define ND 64
#define NCHUNK 128  // S / 64

typedef __attribute__((ext_vector_type(8))) __bf16 bf16x8;
typedef __attribute__((ext_vector_type(4))) float f32x4;

__device__ __forceinline__ unsigned short f2bf(float x) {
  unsigned int u = __builtin_bit_cast(unsigned int, x);
  unsigned int r = (u + 0x7FFFu + ((u >> 16) & 1u)) >> 16;
  return (unsigned short)r;
}

__device__ __forceinline__ void gload16(const void* g, void* l) {
  __builtin_amdgcn_global_load_lds(
      (const __attribute__((address_space(1))) unsigned int*)g,
      (__attribute__((address_space(3))) unsigned int*)l, 16, 0, 0);
}

#define BAR()                        \
  asm volatile("" ::: "memory");     \
  __builtin_amdgcn_s_barrier();      \
  asm volatile("" ::: "memory")

// ---------------- X fp32 -> bf16 ----------------
__global__ __launch_bounds__(256) void convert_x(const float* __restrict__ x,
                                                 unsigned short* __restrict__ xb) {
  int gt = blockIdx.x * 256 + threadIdx.x;
  const float4* xf = (const float4*)x;
  float4 v0 = xf[gt * 2 + 0];
  float4 v1 = xf[gt * 2 + 1];
  uint4 o;
  o.x = f2bf(v0.x) | ((unsigned)f2bf(v0.y) << 16);
  o.y = f2bf(v0.z) | ((unsigned)f2bf(v0.w) << 16);
  o.z = f2bf(v1.x) | ((unsigned)f2bf(v1.y) << 16);
  o.w = f2bf(v1.z) | ((unsigned)f2bf(v1.w) << 16);
  ((uint4*)xb)[gt] = o;
}

// ---------------- W [k][n] fp32 -> Wt [3][n][k] bf16 (K scaled by 1/8) -------
__global__ __launch_bounds__(256) void transpose_w(const float* __restrict__ w0,
                                                   const float* __restrict__ w1,
                                                   const float* __restrict__ w2,
                                                   unsigned short* __restrict__ wt) {
  __shared__ float tile[32][33];
  int wi = blockIdx.z;
  const float* w = (wi == 0) ? w0 : ((wi == 1) ? w1 : w2);
  float scale = (wi == 1) ? 0.125f : 1.0f;  // 1/sqrt(D) folded into Wk
  int k0 = blockIdx.x * 32, n0 = blockIdx.y * 32;
  int tx = threadIdx.x, ty = threadIdx.y;  // 32 x 8
#pragma unroll
  for (int i = 0; i < 4; i++)
    tile[ty + i * 8][tx] = w[(k0 + ty + i * 8) * NHID + n0 + tx];
  __syncthreads();
#pragma unroll
  for (int i = 0; i < 4; i++)
    wt[(wi * NHID + n0 + ty + i * 8) * NHID + k0 + tx] =
        f2bf(tile[tx][ty + i * 8] * scale);
}

// ---------------- QKV GEMM: 256x256, BK=64, 8 waves, 4-phase/K-tile pipeline -
// (unchanged from round 4: 224us, MfmaUtil 40%, 0 bank conflicts)
#define OFF_A0 0
#define OFF_A1 16384
#define OFF_B0 32768
#define OFF_B1 49152

__device__ __forceinline__ void stage_half(const unsigned short* __restrict__ src,
                                           size_t row0, int kt, char* ldsbase,
                                           int tid) {
#pragma unroll
  for (int i = 0; i < 2; i++) {
    int g = tid + i * 512;         // 1024 granules of 16B per 16KB half-tile
    int r = g >> 3;                // 8 granules per 128B row
    int slot = (g & 7) ^ (r & 7);  // inverse swizzle on the source side
    gload16(src + (row0 + r) * NHID + kt * 64 + slot * 8, ldsbase + g * 16);
  }
}

__device__ __forceinline__ bf16x8 lds_frag(const char* base, int r, int ks,
                                           int lg) {
  int byte = (r * 128 + ks * 64 + lg * 16) ^ ((r & 7) << 4);
  return *reinterpret_cast<const bf16x8*>(base + byte);
}

#define MFMA16(ACC, AF, BF)                                                  \
  __builtin_amdgcn_s_setprio(1);                                            \
  _Pragma("unroll") for (int mi = 0; mi < 4; mi++)                          \
      _Pragma("unroll") for (int ni = 0; ni < 2; ni++)                      \
          _Pragma("unroll") for (int ks = 0; ks < 2; ks++)                  \
              ACC[mi][ni] = __builtin_amdgcn_mfma_f32_16x16x32_bf16(        \
                  AF[mi][ks], BF[ni][ks], ACC[mi][ni], 0, 0, 0);            \
  __builtin_amdgcn_s_setprio(0)

__global__ __launch_bounds__(512, 2) void gemm_qkv(
    const unsigned short* __restrict__ xb, const unsigned short* __restrict__ wt,
    unsigned short* __restrict__ qg, unsigned short* __restrict__ kg,
    unsigned short* __restrict__ vg) {
  __shared__ alignas(16) char smem[131072];  // 2 dbuf x 64KB
  int bid = blockIdx.x;
  // XCD-aware swizzle (bijective: 1536 % 8 == 0)
  int wg = (bid & 7) * 192 + (bid >> 3);
  int bm = wg / 12, bn = wg % 12;  // bn fast: A panel reused across 12 bn
  int tid = threadIdx.x;
  int l = tid & 63, lg = l >> 4, lm = l & 15;
  int w = tid >> 6, wm = w >> 2, wn = w & 3;  // 2x4 waves

  const size_t arow0 = (size_t)bm * 256;
  const size_t brow0 = (size_t)bn * 256;

  // prologue: tile0 complete + tile1 {Ah0,Bh0}; wait all but last 2 halves
  stage_half(xb, arow0, 0, smem + OFF_A0, tid);
  stage_half(wt, brow0, 0, smem + OFF_B0, tid);
  stage_half(xb, arow0 + 128, 0, smem + OFF_A1, tid);
  stage_half(wt, brow0 + 128, 0, smem + OFF_B1, tid);
  stage_half(xb, arow0, 1, smem + 65536 + OFF_A0, tid);
  stage_half(wt, brow0, 1, smem + 65536 + OFF_B0, tid);
  asm volatile("s_waitcnt vmcnt(4)" ::: "memory");
  BAR();

  f32x4 acc[2][2][4][2] = {};  // [qm][qn][mi][ni] -> AGPRs
  bf16x8 a[4][2], b0[2][2], b1[2][2];

#pragma unroll 1
  for (int t = 0; t < 16; ++t) {
    char* cb = smem + (t & 1) * 65536;
    char* nb = smem + ((t & 1) ^ 1) * 65536;

    // ---- phase 1 (qm0,qn0): read A0 + B0 ; stage (t+1).Ah1 ----
#pragma unroll
    for (int mi = 0; mi < 4; mi++)
#pragma unroll
      for (int ks = 0; ks < 2; ks++)
        a[mi][ks] = lds_frag(cb + OFF_A0, wm * 64 + mi * 16 + lm, ks, lg);
#pragma unroll
    for (int ni = 0; ni < 2; ni++)
#pragma unroll
      for (int ks = 0; ks < 2; ks++)
        b0[ni][ks] = lds_frag(cb + OFF_B0, wn * 32 + ni * 16 + lm, ks, lg);
    if (t < 15) stage_half(xb, arow0 + 128, t + 1, nb + OFF_A1, tid);
    BAR();
    MFMA16(acc[0][0], a, b0);
    BAR();

    // ---- phase 2 (qm0,qn1): read B1 ; stage (t+1).Bh1 ----
#pragma unroll
    for (int ni = 0; ni < 2; ni++)
#pragma unroll
      for (int ks = 0; ks < 2; ks++)
        b1[ni][ks] = lds_frag(cb + OFF_B1, wn * 32 + ni * 16 + lm, ks, lg);
    if (t < 15) stage_half(wt, brow0 + 128, t + 1, nb + OFF_B1, tid);
    BAR();
    MFMA16(acc[0][1], a, b1);
    BAR();

    // ---- phase 3 (qm1,qn0): read A1 ; stage (t+2).Ah0 (slot free since P2) --
#pragma unroll
    for (int mi = 0; mi < 4; mi++)
#pragma unroll
      for (int ks = 0; ks < 2; ks++)
        a[mi][ks] = lds_frag(cb + OFF_A1, wm * 64 + mi * 16 + lm, ks, lg);
    if (t < 14) stage_half(xb, arow0, t + 2, cb + OFF_A0, tid);
    BAR();
    MFMA16(acc[1][0], a, b0);
    BAR();

    // ---- phase 4 (qm1,qn1): stage (t+2).Bh0 ; counted vmcnt ----
    if (t < 14) {
      stage_half(wt, brow0, t + 2, cb + OFF_B0, tid);
      asm volatile("s_waitcnt vmcnt(4)" ::: "memory");
    } else {
      asm volatile("s_waitcnt vmcnt(0)" ::: "memory");
    }
    BAR();
    MFMA16(acc[1][1], a, b1);
    BAR();
  }

  // epilogue: scatter to [b][h][s][d] bf16; tile spans one weight (bn>>2)
  int wsel = bn >> 2;
  unsigned short* dst = (wsel == 0) ? qg : ((wsel == 1) ? kg : vg);
#pragma unroll
  for (int qm = 0; qm < 2; qm++)
#pragma unroll
    for (int qn = 0; qn < 2; qn++)
#pragma unroll
      for (int mi = 0; mi < 4; mi++)
#pragma unroll
        for (int ni = 0; ni < 2; ni++)
#pragma unroll
          for (int rr = 0; rr < 4; rr++) {
            int gm = bm * 256 + qm * 128 + wm * 64 + mi * 16 + lg * 4 + rr;
            int n = (bn & 3) * 256 + qn * 128 + wn * 32 + ni * 16 + lm;
            int b = gm >> 13, s = gm & (NS - 1);
            int h = n >> 6, d = n & (ND - 1);
            dst[(((size_t)(b * NH + h) * NS) + s) * ND + d] =
                f2bf(acc[qm][qn][mi][ni][rr]);
          }
}

// ---------------- Local attention: block = (chunk c, head h, batch b) --------
// 4 waves x 16 q-rows. SWAPPED QK^T (S^T = mfma(K,Q)): lane holds
// S[q = w*16+lm][kv = nt*16+lg*4+r] -> q lane-fixed: softmax reduce = 2 shfl,
// P packs 4-kv-contiguous -> 8 x ds_write_b64, normalization folded into P.
__global__ __launch_bounds__(256, 4) void attn_local(
    const unsigned short* __restrict__ qg, const unsigned short* __restrict__ kg,
    const unsigned short* __restrict__ vg, float* __restrict__ out) {
  __shared__ alignas(16) char lds[40960];
  unsigned short* qs = (unsigned short*)lds;             // [64][64] swz, 8KB
  unsigned short* ks2 = (unsigned short*)(lds + 8192);   // [128][64] swz, 16KB
  unsigned short* vts = (unsigned short*)(lds + 24576);  // [64][128] swz, 16KB
  char* psb = lds;  // P [64][128] swz, 16KB — ALIASES qs + ks2[0:64) after b2
  int c = blockIdx.x, h = blockIdx.y, b = blockIdx.z;
  int t = threadIdx.x;
  int w = t >> 6, l = t & 63, lg = l >> 4, lm = l & 15;
  size_t bhbase = (size_t)(b * NH + h) * NS * ND;
  int kv0 = (c - 1) * 64;  // global s of kv col 0 (negative for c==0: masked)

  // ---- batched global loads: Q(2) + K(4) + V(4) uint4 all in flight ----
  int g0 = t, g1 = t + 256;
  int qrow0 = g0 >> 3, qcc0 = g0 & 7, qrow1 = g1 >> 3, qcc1 = g1 & 7;
  uint4 qv0 = *reinterpret_cast<const uint4*>(
      qg + bhbase + (size_t)(c * 64 + qrow0) * ND + qcc0 * 8);
  uint4 qv1 = *reinterpret_cast<const uint4*>(
      qg + bhbase + (size_t)(c * 64 + qrow1) * ND + qcc1 * 8);
  uint4 kvr[4];
  int krow[4], kcc[4];
#pragma unroll
  for (int i = 0; i < 4; i++) {
    int g = t + i * 256;
    krow[i] = g >> 3;
    kcc[i] = g & 7;
    int s = kv0 + krow[i];
    if (s < 0) s = 0;  // garbage rows fully masked later
    kvr[i] =
        *reinterpret_cast<const uint4*>(kg + bhbase + (size_t)s * ND + kcc[i] * 8);
  }
  int kq = t >> 1, half = t & 1;
  int sv = kv0 + kq;
  if (sv < 0) sv = 0;
  uint4 vreg[4];
#pragma unroll
  for (int i = 0; i < 4; i++)
    vreg[i] = *reinterpret_cast<const uint4*>(vg + bhbase + (size_t)sv * ND +
                                              half * 32 + i * 8);

  // ---- LDS writes: Q [64][64] swz, K [128][64] swz ----
  *reinterpret_cast<uint4*>(lds + ((qrow0 * 128 + qcc0 * 16) ^ ((qrow0 & 7) << 4))) =
      qv0;
  *reinterpret_cast<uint4*>(lds + ((qrow1 * 128 + qcc1 * 16) ^ ((qrow1 & 7) << 4))) =
      qv1;
#pragma unroll
  for (int i = 0; i < 4; i++)
    *reinterpret_cast<uint4*>(
        lds + 8192 + ((krow[i] * 128 + kcc[i] * 16) ^ ((krow[i] & 7) << 4))) =
        kvr[i];
  __syncthreads();  // b1

  // ---- S^T = K Q^T : wave w owns q cols [w*16, w*16+16), all 128 kv rows ----
  bf16x8 qa[2];
#pragma unroll
  for (int ks = 0; ks < 2; ks++) {
    int row = w * 16 + lm;
    int byte = (row * 128 + (ks * 32 + lg * 8) * 2) ^ ((row & 7) << 4);
    qa[ks] = *reinterpret_cast<const bf16x8*>((char*)qs + byte);
  }
  f32x4 sf[8];
#pragma unroll
  for (int nt = 0; nt < 8; nt++) {
    f32x4 a = {};
#pragma unroll
    for (int ks = 0; ks < 2; ks++) {
      int n = nt * 16 + lm;
      int byte = (n * 128 + (ks * 32 + lg * 8) * 2) ^ ((n & 7) << 4);
      bf16x8 kb = *reinterpret_cast<const bf16x8*>((char*)ks2 + byte);
      a = __builtin_amdgcn_mfma_f32_16x16x32_bf16(kb, qa[ks], a, 0, 0, 0);
    }
    sf[nt] = a;  // S[q = w*16+lm][kv = nt*16+lg*4+r]
  }

  // ---- masked softmax: q is lane-fixed; reduce across lg groups (2 shfl) ----
  int q = w * 16 + lm;  // local q row, lane-uniform across r
  float m = -1e30f;
#pragma unroll
  for (int nt = 0; nt < 8; nt++)
#pragma unroll
    for (int r = 0; r < 4; r++) {
      int j = nt * 16 + lg * 4 + r;
      bool valid = (j <= q + 64) && (c > 0 || j >= 64);
      if (valid) m = fmaxf(m, sf[nt][r]);
    }
  m = fmaxf(m, __shfl_xor(m, 16, 64));
  m = fmaxf(m, __shfl_xor(m, 32, 64));

  float sum = 0.f;
#pragma unroll
  for (int nt = 0; nt < 8; nt++)
#pragma unroll
    for (int r = 0; r < 4; r++) {
      int j = nt * 16 + lg * 4 + r;
      bool valid = (j <= q + 64) && (c > 0 || j >= 64);
      float p = valid ? __expf(sf[nt][r] - m) : 0.0f;
      sf[nt][r] = p;
      sum += p;
    }
  sum += __shfl_xor(sum, 16, 64);
  sum += __shfl_xor(sum, 32, 64);
  float rn = 1.0f / sum;

  __syncthreads();  // b2: all QK^T reads of qs/ks2 done -> P may overwrite them

  // write normalized P (bf16) to aliased LDS [q][kv], 8B packed per nt
#pragma unroll
  for (int nt = 0; nt < 8; nt++) {
    unsigned int lo =
        f2bf(sf[nt][0] * rn) | ((unsigned)f2bf(sf[nt][1] * rn) << 16);
    unsigned int hi =
        f2bf(sf[nt][2] * rn) | ((unsigned)f2bf(sf[nt][3] * rn) << 16);
    int kvb = nt * 16 + lg * 4;
    int byte = (q * 256 + kvb * 2) ^ ((q & 7) << 4);
    *reinterpret_cast<uint2*>(psb + byte) = make_uint2(lo, hi);
  }
  // scatter V regs -> vts[d][kv] transposed, col ^= (d&7)<<3
  {
    unsigned short* vtse = (unsigned short*)vts;
#pragma unroll
    for (int i = 0; i < 4; i++) {
      int d0 = half * 32 + i * 8;
      unsigned int u[4] = {vreg[i].x, vreg[i].y, vreg[i].z, vreg[i].w};
#pragma unroll
      for (int j = 0; j < 8; j++) {
        unsigned short val = (unsigned short)(u[j >> 1] >> ((j & 1) * 16));
        vtse[(d0 + j) * 128 + (kq ^ (j << 3))] = val;  // (d0+j)&7 == j
      }
    }
  }
  __syncthreads();  // b3

  // ---- O = P V : A = P rows (q), B = vts rows (d); P pre-normalized ----
  bf16x8 pa[4];
#pragma unroll
  for (int ks = 0; ks < 4; ks++) {
    int byte = (q * 256 + (ks * 32 + lg * 8) * 2) ^ ((q & 7) << 4);
    pa[ks] = *reinterpret_cast<const bf16x8*>(psb + byte);
  }
#pragma unroll
  for (int nt = 0; nt < 4; nt++) {
    f32x4 o = {};
#pragma unroll
    for (int ks = 0; ks < 4; ks++) {
      int dn = nt * 16 + lm;
      int byte = (dn * 256 + (ks * 32 + lg * 8) * 2) ^ ((dn & 7) << 4);
      bf16x8 vb = *reinterpret_cast<const bf16x8*>((char*)vts + byte);
      o = __builtin_amdgcn_mfma_f32_16x16x32_bf16(pa[ks], vb, o, 0, 0, 0);
    }
#pragma unroll
    for (int r = 0; r < 4; r++) {
      int sq = c * 64 + w * 16 + lg * 4 + r;
      int d = nt * 16 + lm;
      out[(size_t)(b * NS + sq) * (NH * ND) + h * ND + d] = o[r];
    }
  }
}

// ---------------- launch ----------------
extern "C" void kernel_launch(void* const* d_in, const int* in_sizes, int n_in,
                              void* d_out, int out_size, void* d_ws, size_t ws_size,
                              hipStream_t stream) {
  const float* hs = (const float*)d_in[0];
  const float* wq = (const float*)d_in[1];
  const float* wk = (const float*)d_in[2];
  const float* wv = (const float*)d_in[3];
  float* out = (float*)d_out;
  char* ws = (char*)d_ws;

  const size_t XB_BYTES = (size_t)NB * NS * NHID * 2;      // 64MB
  const size_t WT_BYTES = (size_t)3 * NHID * NHID * 2;     // 6MB
  const size_t QKV_BYTES = (size_t)NB * NH * NS * ND * 2;  // 64MB each
  unsigned short* xb = (unsigned short*)ws;
  unsigned short* wt = (unsigned short*)(ws + XB_BYTES);
  unsigned short* qg = (unsigned short*)(ws + XB_BYTES + WT_BYTES);
  unsigned short* kg = (unsigned short*)(ws + XB_BYTES + WT_BYTES + QKV_BYTES);
  unsigned short* vg = (unsigned short*)(ws + XB_BYTES + WT_BYTES + 2 * QKV_BYTES);

  hipLaunchKernelGGL(convert_x, dim3((NB * NS * NHID) / (256 * 8)), dim3(256), 0,
                     stream, hs, xb);
  hipLaunchKernelGGL(transpose_w, dim3(32, 32, 3), dim3(32, 8), 0, stream, wq, wk,
                     wv, wt);
  hipLaunchKernelGGL(gemm_qkv, dim3(128 * 12), dim3(512), 0, stream, xb, wt, qg,
                     kg, vg);
  hipLaunchKernelGGL(attn_local, dim3(NCHUNK, NH, NB), dim3(256), 0, stream, qg,
                     kg, vg, out);
}